// Round 10
// baseline (690.327 us; speedup 1.0000x reference)
//
#include <hip/hip_runtime.h>
#include <hip/hip_bf16.h>

#define NN 50000
#define EE 800000
#define DD 512
#define BB 64
#define LL 4
#define OUTC 2
#define EPSV 1e-5f

#define MTG 64                // gemm M-tile (A read exactly once over the grid)
#define BKG 64                // gemm K-step (2 mfma-K per barrier pair)
#define HV8 (NN * DD / 8)     // 3,200,000 vectorized x->fp8 items

typedef _Float16 halfx8 __attribute__((ext_vector_type(8)));
typedef float floatx4 __attribute__((ext_vector_type(4)));
typedef float floatx2 __attribute__((ext_vector_type(2)));

// ---------------- OCP e4m3 fp8 conversion (HW path on gfx950) ----------------
#if defined(__has_builtin)
#if __has_builtin(__builtin_amdgcn_cvt_pk_f32_fp8) && __has_builtin(__builtin_amdgcn_cvt_pk_fp8_f32)
#define HW_FP8 1
#endif
#endif

#ifdef HW_FP8
__device__ __forceinline__ floatx2 f8x2_lo(unsigned int u) {
    return __builtin_amdgcn_cvt_pk_f32_fp8(u, 0);   // bytes 0,1
}
__device__ __forceinline__ floatx2 f8x2_hi(unsigned int u) {
    return __builtin_amdgcn_cvt_pk_f32_fp8(u, 1);   // bytes 2,3
}
__device__ __forceinline__ unsigned int f8_pack_lo(float a, float b, unsigned int old) {
    return (unsigned int)__builtin_amdgcn_cvt_pk_fp8_f32(a, b, (int)old, 0);
}
__device__ __forceinline__ unsigned int f8_pack_hi(float a, float b, unsigned int old) {
    return (unsigned int)__builtin_amdgcn_cvt_pk_fp8_f32(a, b, (int)old, 1);
}
__device__ __forceinline__ unsigned char f8_enc1(float v) {
    return (unsigned char)(__builtin_amdgcn_cvt_pk_fp8_f32(v, v, 0, 0) & 0xff);
}
#else
// software OCP e4m3fn fallback (self-consistent encode/decode)
__device__ __forceinline__ float f8_dec1(unsigned int b) {
    unsigned int s = b & 0x80u, e = (b >> 3) & 15u, m = b & 7u;
    float v = e ? __uint_as_float(((e + 120u) << 23) | (m << 20))
                : (float)m * 0.001953125f;
    return s ? -v : v;
}
__device__ __forceinline__ floatx2 f8x2_lo(unsigned int u) {
    floatx2 r; r[0] = f8_dec1(u & 0xffu); r[1] = f8_dec1((u >> 8) & 0xffu); return r;
}
__device__ __forceinline__ floatx2 f8x2_hi(unsigned int u) {
    floatx2 r; r[0] = f8_dec1((u >> 16) & 0xffu); r[1] = f8_dec1((u >> 24) & 0xffu); return r;
}
__device__ __forceinline__ unsigned char f8_enc1(float x) {
    unsigned int s = (__float_as_uint(x) >> 24) & 0x80u;
    float a = fabsf(x);
    if (a < 0.015625f) {
        int m = (int)(a * 512.0f + 0.5f);
        return (unsigned char)(s | (unsigned int)m);
    }
    unsigned int ab = __float_as_uint(a);
    int e = (int)(ab >> 23) - 127;
    unsigned int m23 = ab & 0x7fffffu;
    unsigned int r = m23 + 0x7ffffu + ((m23 >> 20) & 1u);   // RNE to 3 mantissa bits
    if (r >= 0x800000u) { e++; r -= 0x800000u; }
    unsigned int m = r >> 20;
    if (e > 8 || (e == 8 && m >= 7u)) return (unsigned char)(s | 0x7eu);  // clamp 448
    return (unsigned char)(s | ((unsigned int)(e + 7) << 3) | m);
}
__device__ __forceinline__ unsigned int f8_pack_lo(float a, float b, unsigned int old) {
    return (old & 0xffff0000u) | (unsigned int)f8_enc1(a) | ((unsigned int)f8_enc1(b) << 8);
}
__device__ __forceinline__ unsigned int f8_pack_hi(float a, float b, unsigned int old) {
    return (old & 0x0000ffffu) | ((unsigned int)f8_enc1(a) << 16) | ((unsigned int)f8_enc1(b) << 24);
}
#endif

__device__ __forceinline__ floatx4 mfma16h(halfx8 a, halfx8 b, floatx4 c) {
    return __builtin_amdgcn_mfma_f32_16x16x32_f16(a, b, c, 0, 0, 0);
}

// async global->LDS, 16B per lane. LDS dest = wave-uniform base + lane*16.
__device__ __forceinline__ void ldg2lds16(const _Float16* g, _Float16* l) {
    __builtin_amdgcn_global_load_lds(
        (const __attribute__((address_space(1))) unsigned int*)g,
        (__attribute__((address_space(3))) unsigned int*)l, 16, 0, 0);
}

// SWIZZLE SCHEME (G21: gload_lds writes linearly -> pre-swizzle in GLOBAL,
// unswizzle on ds_read). All GEMM-consumed fp16 rows (S and WT) are stored
// with their 16-B granules XOR-permuted by (row&7) WITHIN each 128-B window.
// Producers stay fully coalesced (pure lane permutation); the ds_read_b128
// then lands exactly 8 words/bank = the wave64 b128 floor.

// ---------------- fused prep: x->fp8 + WT transpose (pre-swizzled) + BN fold +
// packed u64 edge atomics (fire-and-forget: no returned value -> no chain) ----
__global__ void k_prep(const float* __restrict__ x, const float* __restrict__ Wc,
                       const int* __restrict__ ei, const int* __restrict__ sd,
                       const float* __restrict__ bc, const float* __restrict__ gamma,
                       const float* __restrict__ beta, const float* __restrict__ rmean,
                       const float* __restrict__ rvar,
                       unsigned char* __restrict__ X8, _Float16* __restrict__ WT,
                       unsigned long long* __restrict__ degcnt,
                       float* __restrict__ scb, float* __restrict__ shb) {
    int i = blockIdx.x * blockDim.x + threadIdx.x;
    if (i < HV8) {
        const float4* xp = (const float4*)x + (size_t)i * 2;
        float4 v0 = xp[0], v1 = xp[1];
        unsigned int u0 = 0, u1 = 0;
        u0 = f8_pack_lo(v0.x, v0.y, u0);
        u0 = f8_pack_hi(v0.z, v0.w, u0);
        u1 = f8_pack_lo(v1.x, v1.y, u1);
        u1 = f8_pack_hi(v1.z, v1.w, u1);
        uint2 q; q.x = u0; q.y = u1;
        ((uint2*)X8)[i] = q;
    }
    if (i < LL * DD * DD) {
        // i = (l<<18)+(n<<9)+k, k fastest -> coalesced write (pure lane perm);
        // granule swizzle: k bits 3..5 ^= n&7 (stays inside the 64-half window)
        int l = i >> 18;
        int rem = i & ((DD * DD) - 1);
        int n = rem >> 9;
        int k = rem & (DD - 1);
        WT[(l << 18) + (n << 9) + (k ^ ((n & 7) << 3))] =
            (_Float16)Wc[(l << 18) + (k << 9) + n];
    }
    if (i < LL * DD) {
        // out = gamma*(agg + bc - rmean)*rs + beta = sc*agg + sh
        float rs = rsqrtf(rvar[i] + EPSV);
        float scv = gamma[i] * rs;
        scb[i] = scv;
        shb[i] = scv * (bc[i] - rmean[i]) + beta[i];
    }
    if ((i & 3) == 0) {
        int e = i >> 2;
        if (e < EE) {
            int c = ei[EE + e];
            unsigned long long v =
                0x100000000ull + (unsigned long long)((sd[e] == 1) ? 10u : 7u);
            atomicAdd(&degcnt[c], v);
        }
    }
}

// ---------------- scan block 1 (+ fused dis + fused graph bounds) ----------------
__global__ void k_scan1(const unsigned long long* __restrict__ degcnt,
                        int* __restrict__ rowptr, int* __restrict__ bsum,
                        float* __restrict__ dis, const int* __restrict__ batch,
                        int* __restrict__ gstart, int* __restrict__ gend) {
    __shared__ int sh[256];
    const int t = threadIdx.x;
    const int i = blockIdx.x * 256 + t;
    int cntv = 0;
    if (i < NN) {
        unsigned long long dc = degcnt[i];
        cntv = (int)(dc >> 32);
        float degv = 0.1f * (float)(unsigned int)(dc & 0xffffffffu);
        dis[i] = rsqrtf(fmaxf(degv + 1.0f, EPSV));   // +1 = self-loop weight
        int g = batch[i];
        int gp = (i == 0) ? -1 : batch[i - 1];
        if (g != gp) gstart[g] = i;
        int gn = (i == NN - 1) ? BB : batch[i + 1];
        if (g != gn) gend[g] = i + 1;
    }
    sh[t] = cntv;
    __syncthreads();
    for (int off = 1; off < 256; off <<= 1) {
        int y = (t >= off) ? sh[t - off] : 0;
        __syncthreads();
        if (t >= off) sh[t] += y;
        __syncthreads();
    }
    if (i < NN) rowptr[i] = sh[t] - cntv;   // exclusive
    if (t == 255) bsum[blockIdx.x] = sh[255];
}

// parallel single-block scan over the 196 block sums
__global__ void k_scan2(int* __restrict__ bsum, int* __restrict__ rowptr, int nb) {
    __shared__ int sh[256];
    const int t = threadIdx.x;
    int v = (t < nb) ? bsum[t] : 0;
    sh[t] = v;
    __syncthreads();
    for (int off = 1; off < 256; off <<= 1) {
        int y = (t >= off) ? sh[t - off] : 0;
        __syncthreads();
        if (t >= off) sh[t] += y;
        __syncthreads();
    }
    if (t < nb) bsum[t] = sh[t] - v;    // exclusive
    if (t == 255) rowptr[NN] = sh[255]; // total
}

__global__ void k_scan3(int* __restrict__ rowptr, const int* __restrict__ bsum) {
    int i = blockIdx.x * blockDim.x + threadIdx.x;
    if (i < NN) rowptr[i] += bsum[i >> 8];
}

// ---------------- CSR fill: 4-edge ILP (atomic-latency amortization) ---------
// R8 counters: 66.6 us at 1.38 TB/s, VALUBusy 0.7% -- one RETURNING atomic per
// thread serializes ~400+ cyc with nothing else in flight. Each thread now
// handles edges {e, e+E/4, e+2E/4, e+3E/4} (each quarter stays coalesced):
// 4 independent atomic+gather chains in flight -> ~4x issue efficiency.
// Slot assignment was already nondeterministic (atomic race); summation order
// in k_agg changes only within fp8-dominated noise (absmax stable across rounds).
__global__ void k_fill(const int* __restrict__ ei, const int* __restrict__ sd,
                       const float* __restrict__ dis, const int* __restrict__ rowptr,
                       int* __restrict__ fill, uint2* __restrict__ edges) {
    const int E4 = EE / 4;
    int e = blockIdx.x * blockDim.x + threadIdx.x;
    if (e >= E4) return;
    int sv[4], cv[4];
    float wv[4];
#pragma unroll
    for (int u = 0; u < 4; u++) {
        const int idx = e + u * E4;
        sv[u] = ei[idx];
        cv[u] = ei[EE + idx];
        wv[u] = (sd[idx] == 1) ? 1.0f : 0.7f;
    }
    float dsv[4], dcv[4];
#pragma unroll
    for (int u = 0; u < 4; u++) { dsv[u] = dis[sv[u]]; dcv[u] = dis[cv[u]]; }
    int rp[4], pv[4];
#pragma unroll
    for (int u = 0; u < 4; u++) rp[u] = rowptr[cv[u]];
#pragma unroll
    for (int u = 0; u < 4; u++) pv[u] = atomicAdd(&fill[cv[u]], 1);
#pragma unroll
    for (int u = 0; u < 4; u++) {
        uint2 ev;
        ev.x = (unsigned int)sv[u];
        ev.y = __float_as_uint(dsv[u] * wv[u] * dcv[u]);
        edges[rp[u] + pv[u]] = ev;
    }
}

// ---------------- split gather: S[n] = sum norm_e * H8[src] + dn^2 * H8[n] ----
// Measured pattern floor: ~62 us @ ~3.95 TB/s, FETCH ~190 MB (R5/R7/R9; two
// cache-model attacks failed -- R7 channel-split and R2-era fusion).
__launch_bounds__(256)
__global__ void k_agg(const unsigned char* __restrict__ h8, const int* __restrict__ rowptr,
                      const uint2* __restrict__ edges,
                      const float* __restrict__ dis, _Float16* __restrict__ S) {
    const int n = blockIdx.x * 4 + (threadIdx.x >> 6);
    const int lane = threadIdx.x & 63;
    if (n >= NN) return;
    const float dn = dis[n];
    const float sw = dn * dn;  // self-loop norm
    uint2 q = ((const uint2*)(h8 + (size_t)n * DD))[lane];
    floatx2 acc[4];
    acc[0] = f8x2_lo(q.x) * sw;
    acc[1] = f8x2_hi(q.x) * sw;
    acc[2] = f8x2_lo(q.y) * sw;
    acc[3] = f8x2_hi(q.y) * sw;
    const int s0 = rowptr[n], s1 = rowptr[n + 1];
    int i = s0;
    for (; i + 8 <= s1; i += 8) {
        uint2 ev[8];
        uint2 qv[8];
#pragma unroll
        for (int u = 0; u < 8; u++) ev[u] = edges[i + u];
#pragma unroll
        for (int u = 0; u < 8; u++)
            qv[u] = ((const uint2*)(h8 + (size_t)ev[u].x * DD))[lane];
#pragma unroll
        for (int u = 0; u < 8; u++) {
            const float wv = __uint_as_float(ev[u].y);
            acc[0] += f8x2_lo(qv[u].x) * wv;
            acc[1] += f8x2_hi(qv[u].x) * wv;
            acc[2] += f8x2_lo(qv[u].y) * wv;
            acc[3] += f8x2_hi(qv[u].y) * wv;
        }
    }
    for (; i + 4 <= s1; i += 4) {
        uint2 ev[4];
        uint2 qv[4];
#pragma unroll
        for (int u = 0; u < 4; u++) ev[u] = edges[i + u];
#pragma unroll
        for (int u = 0; u < 4; u++)
            qv[u] = ((const uint2*)(h8 + (size_t)ev[u].x * DD))[lane];
#pragma unroll
        for (int u = 0; u < 4; u++) {
            const float wv = __uint_as_float(ev[u].y);
            acc[0] += f8x2_lo(qv[u].x) * wv;
            acc[1] += f8x2_hi(qv[u].x) * wv;
            acc[2] += f8x2_lo(qv[u].y) * wv;
            acc[3] += f8x2_hi(qv[u].y) * wv;
        }
    }
    for (; i < s1; i++) {
        uint2 ev = edges[i];
        uint2 qb = ((const uint2*)(h8 + (size_t)ev.x * DD))[lane];
        const float wn = __uint_as_float(ev.y);
        acc[0] += f8x2_lo(qb.x) * wn;
        acc[1] += f8x2_hi(qb.x) * wn;
        acc[2] += f8x2_lo(qb.y) * wn;
        acc[3] += f8x2_hi(qb.y) * wn;
    }
    halfx8 hv;
#pragma unroll
    for (int k = 0; k < 4; k++) {
        hv[2 * k] = (_Float16)acc[k][0];
        hv[2 * k + 1] = (_Float16)acc[k][1];
    }
    // granule-swizzled coalesced row store (lane permutation within 128-B wins)
    ((halfx8*)(S + (size_t)n * DD))[lane ^ (n & 7)] = hv;
}

// ---------------- GEMM (R5 structure + packed epilogue) ----------------------
// K-loop is R5-exact (proven <=62 us): MTG=64 x full-N 512, BKG=64, both
// operands staged via global_load_lds, granule-XOR ds_reads at the 8-words/bank
// floor. LDS-bounce epilogue (R7, -42 us): stage the C tile into the dead sB
// ([64][512] fp16, granule-XOR by row&7 -> 2-way-max = free), then each wave
// stores full contiguous rows (1024 B fp16 / 512 B fp8 via cvt_pk repack).
// OUT8=0 (last layer) writes fp16 in-place over A rows (block-row-exclusive).
template <int OUT8>
__launch_bounds__(512)
__global__ void k_gemm(const _Float16* __restrict__ A,
                       const _Float16* __restrict__ B,   // WT layer base, [n][k] swz
                       const float* __restrict__ sc, const float* __restrict__ sh,
                       _Float16* __restrict__ C16, unsigned char* __restrict__ C8) {
    __shared__ _Float16 sA[MTG * BKG];   // 8 KB
    __shared__ _Float16 sB[512 * BKG];   // 64 KB (reused as C bounce)

    const int t = threadIdx.x;
    const int wid = t >> 6;          // 0..7
    const int lane = t & 63;
    const int l15 = lane & 15;
    const int quad = lane >> 4;
    const int m0 = blockIdx.x * MTG;
    const int wc = wid * 64;         // wave col base (8 x 64 = 512)
    const int key = l15 & 7;         // row&7 for every fragment row this lane reads

    // A staging: 512 thr x 16 B = 64 rows x 128 B; row t>>3, granule t&7
    int arow = m0 + (t >> 3);
    if (arow > NN - 1) arow = NN - 1;   // clamp loads; stores guarded
    const _Float16* gA = A + (size_t)arow * DD + (t & 7) * 8;
    _Float16* lA = sA + t * 8;
    // B staging: 8 rounds of 64 rows x 128 B
    const _Float16* gB = B + (size_t)(t >> 3) * DD + (t & 7) * 8;
    _Float16* lB = sB + t * 8;

    floatx4 acc[4][4];
#pragma unroll
    for (int i = 0; i < 4; i++)
#pragma unroll
        for (int j = 0; j < 4; j++) acc[i][j] = (floatx4){0.f, 0.f, 0.f, 0.f};

    for (int k0 = 0; k0 < DD; k0 += BKG) {
        __syncthreads();   // previous compute done before overwriting LDS
        ldg2lds16(gA + k0, lA);
#pragma unroll
        for (int r = 0; r < 8; r++)
            ldg2lds16(gB + (size_t)r * 64 * DD + k0, lB + r * 4096);
        __syncthreads();   // compiler drains vmcnt before barrier

#pragma unroll
        for (int cc = 0; cc < 2; cc++) {
            halfx8 a[4], b[4];
            const int goff = ((cc * 4 + quad) ^ key) * 8;   // unswizzle granule
#pragma unroll
            for (int i = 0; i < 4; i++)
                a[i] = *(const halfx8*)&sA[(i * 16 + l15) * BKG + goff];
#pragma unroll
            for (int j = 0; j < 4; j++)
                b[j] = *(const halfx8*)&sB[(wc + j * 16 + l15) * BKG + goff];
#pragma unroll
            for (int i = 0; i < 4; i++)
#pragma unroll
                for (int j = 0; j < 4; j++)
                    acc[i][j] = mfma16h(a[i], b[j], acc[i][j]);
        }
    }

    // ---- packed epilogue: affine+ReLU -> bounce (sB) -> wide row stores ----
    __syncthreads();                 // all sB fragment reads complete
    _Float16* bounce = sB;           // [64 rows][512 halves], granule-XOR row&7
#pragma unroll
    for (int j = 0; j < 4; j++) {
        const int gcol = wc + j * 16 + l15;
        const float scv = sc[gcol];
        const float shv = sh[gcol];
#pragma unroll
        for (int i = 0; i < 4; i++) {
#pragma unroll
            for (int r = 0; r < 4; r++) {
                const int row = i * 16 + quad * 4 + r;
                float v = fmaxf(fmaf(scv, acc[i][j][r], shv), 0.f);
                bounce[row * DD + (gcol ^ ((row & 7) << 3))] = (_Float16)v;
            }
        }
    }
    __syncthreads();
    if (OUT8) {
        // fp8 out: 4 iters; half-wave writes a full contiguous 512 B row
#pragma unroll
        for (int p = 0; p < 4; p++) {
            const int G = p * 512 + t;
            const int row = G >> 5;
            const int c = G & 31;              // 16-byte output granule in row
            const int rk = row & 7;
            const int g0 = (2 * c) ^ rk;       // halves 16c..16c+7 live here
            halfx8 ha = *(const halfx8*)&bounce[row * DD + g0 * 8];
            halfx8 hb = *(const halfx8*)&bounce[row * DD + (g0 ^ 1) * 8];
            unsigned int u0 = 0, u1 = 0, u2 = 0, u3 = 0;
            u0 = f8_pack_lo((float)ha[0], (float)ha[1], u0);
            u0 = f8_pack_hi((float)ha[2], (float)ha[3], u0);
            u1 = f8_pack_lo((float)ha[4], (float)ha[5], u1);
            u1 = f8_pack_hi((float)ha[6], (float)ha[7], u1);
            u2 = f8_pack_lo((float)hb[0], (float)hb[1], u2);
            u2 = f8_pack_hi((float)hb[2], (float)hb[3], u2);
            u3 = f8_pack_lo((float)hb[4], (float)hb[5], u3);
            u3 = f8_pack_hi((float)hb[6], (float)hb[7], u3);
            const int grow = m0 + row;
            if (grow < NN) {
                uint4 qo; qo.x = u0; qo.y = u1; qo.z = u2; qo.w = u3;
                *(uint4*)(C8 + (size_t)grow * DD + c * 16) = qo;
            }
        }
    } else {
        // fp16 out: 8 iters; wave writes a full contiguous 1024 B row
#pragma unroll
        for (int p = 0; p < 8; p++) {
            const int g = p * 512 + t;
            const int row = g >> 6;
            const int c8 = g & 63;             // 8-half output granule in row
            const int grow = m0 + row;
            if (grow < NN) {
                halfx8 hv = *(const halfx8*)
                    &bounce[row * DD + ((c8 ^ (row & 7)) << 3)];
                *(halfx8*)(C16 + (size_t)grow * DD + c8 * 8) = hv;
            }
        }
    }
}

// ---------------- mean/max pooling (8 slices per graph) ----------------
__launch_bounds__(512)
__global__ void k_pool(const _Float16* __restrict__ H,
                       const int* __restrict__ gstart, const int* __restrict__ gend,
                       float* __restrict__ psum, unsigned int* __restrict__ pmax) {
    const int g = blockIdx.x;
    const int sl = blockIdx.y;
    const int c = threadIdx.x;
    const int s0 = gstart[g], e0 = gend[g];
    if (e0 <= s0) return;
    const int len = e0 - s0;
    const int chunk = (len + 7) >> 3;
    const int lo = s0 + sl * chunk;
    const int hi = min(lo + chunk, e0);
    float sum = 0.f, mx = 0.f;
    for (int n = lo; n < hi; n++) {
        float v = (float)H[(size_t)n * DD + c];
        sum += v;
        mx = fmaxf(mx, v);
    }
    if (lo < hi) {
        atomicAdd(&psum[g * DD + c], sum);
        atomicMax(&pmax[g * DD + c], __float_as_uint(fmaxf(mx, 0.f)));  // h >= 0
    }
}

// ---------------- final linear + log_softmax: one wave per graph ----------------
__launch_bounds__(64)
__global__ void k_final(const float* __restrict__ psum, const unsigned int* __restrict__ pmax,
                        const int* __restrict__ gstart, const int* __restrict__ gend,
                        const float* __restrict__ Wlin, const float* __restrict__ blin,
                        float* __restrict__ out) {
    const int g = blockIdx.x;
    const int lane = threadIdx.x;
    int cntg = gend[g] - gstart[g];
    if (cntg < 1) cntg = 1;   // empty graph: psum/pmax are 0, inv irrelevant
    const float inv = 1.0f / (float)cntg;
    float z0 = 0.f, z1 = 0.f;
#pragma unroll
    for (int j = 0; j < 8; j++) {
        const int k = j * 64 + lane;
        float mean = psum[g * DD + k] * inv;
        float mx = __uint_as_float(pmax[g * DD + k]);
        z0 += mean * Wlin[k * OUTC + 0] + mx * Wlin[(DD + k) * OUTC + 0];
        z1 += mean * Wlin[k * OUTC + 1] + mx * Wlin[(DD + k) * OUTC + 1];
    }
#pragma unroll
    for (int off = 32; off > 0; off >>= 1) {
        z0 += __shfl_down(z0, off);
        z1 += __shfl_down(z1, off);
    }
    if (lane == 0) {
        z0 += blin[0];
        z1 += blin[1];
        float m = fmaxf(z0, z1);
        float ls = m + logf(expf(z0 - m) + expf(z1 - m));
        out[g * OUTC + 0] = z0 - ls;
        out[g * OUTC + 1] = z1 - ls;
    }
}

extern "C" void kernel_launch(void* const* d_in, const int* in_sizes, int n_in,
                              void* d_out, int out_size, void* d_ws, size_t ws_size,
                              hipStream_t stream) {
    const float* x = (const float*)d_in[0];
    const int* ei = (const int*)d_in[1];
    const int* batch = (const int*)d_in[2];
    const int* sd = (const int*)d_in[3];
    const float* Wc = (const float*)d_in[4];
    const float* bc = (const float*)d_in[5];
    const float* gamma = (const float*)d_in[6];
    const float* beta = (const float*)d_in[7];
    const float* rmean = (const float*)d_in[8];
    const float* rvar = (const float*)d_in[9];
    const float* Wlin = (const float*)d_in[10];
    const float* blin = (const float*)d_in[11];
    float* out = (float*)d_out;

    char* p = (char*)d_ws;
    auto alloc = [&](size_t bytes) {
        char* r = p;
        p += (bytes + 255) & ~(size_t)255;
        return r;
    };
    // All buffers DISJOINT (gather reads X8 while writing S concurrently).
    _Float16* S = (_Float16*)alloc((size_t)NN * DD * 2);        // 51.2 MB
    unsigned char* X8a = (unsigned char*)alloc((size_t)NN * DD);// 25.6 MB
    unsigned char* X8b = (unsigned char*)alloc((size_t)NN * DD);// 25.6 MB
    _Float16* WT = (_Float16*)alloc((size_t)LL * DD * DD * 2);
    float* scb = (float*)alloc(LL * DD * 4);
    float* shb = (float*)alloc(LL * DD * 4);
    uint2* edges = (uint2*)alloc((size_t)EE * 8);   // fully written by k_fill (no zeroing)
    // --- zero-initialized region starts here (hipMemsetAsync) ---
    char* zbase = p;
    unsigned long long* degcnt = (unsigned long long*)alloc(NN * 8);
    float* dis = (float*)alloc(NN * 4);
    int* fill = (int*)alloc(NN * 4);
    int* rowptr = (int*)alloc((NN + 1) * 4);
    int* bsum = (int*)alloc(256 * 4);
    int* gstart = (int*)alloc(BB * 4);
    int* gend = (int*)alloc(BB * 4);
    float* psum = (float*)alloc(BB * DD * 4);
    unsigned int* pmax = (unsigned int*)alloc(BB * DD * 4);
    size_t zbytes = (size_t)(p - zbase);
    (void)ws_size; (void)in_sizes; (void)n_in; (void)out_size;

    const int nb256 = (NN + 255) / 256;          // 196
    const int fb256 = (EE / 4 + 255) / 256;      // 782 (4 edges/thread)

    hipMemsetAsync(zbase, 0, zbytes, stream);
    k_prep<<<(HV8 + 255) / 256, 256, 0, stream>>>(x, Wc, ei, sd, bc, gamma, beta,
                                                  rmean, rvar, X8a, WT, degcnt, scb, shb);
    k_scan1<<<nb256, 256, 0, stream>>>(degcnt, rowptr, bsum, dis, batch, gstart, gend);
    k_scan2<<<1, 256, 0, stream>>>(bsum, rowptr, nb256);
    k_scan3<<<nb256, 256, 0, stream>>>(rowptr, bsum);
    k_fill<<<fb256, 256, 0, stream>>>(ei, sd, dis, rowptr, fill, edges);

    const int ggrid = (NN + MTG - 1) / MTG;   // 782 blocks
    unsigned char* bufs[2] = {X8a, X8b};
    int cur = 0;
    for (int l = 0; l < LL; l++) {
        k_agg<<<(NN + 3) / 4, 256, 0, stream>>>(bufs[cur], rowptr, edges, dis, S);
        if (l < LL - 1)
            k_gemm<1><<<ggrid, 512, 0, stream>>>(S, WT + (size_t)l * DD * DD,
                                                 scb + l * DD, shb + l * DD,
                                                 nullptr, bufs[cur ^ 1]);
        else
            k_gemm<0><<<ggrid, 512, 0, stream>>>(S, WT + (size_t)l * DD * DD,
                                                 scb + l * DD, shb + l * DD,
                                                 S, nullptr);
        cur ^= 1;
    }

    k_pool<<<dim3(BB, 8), 512, 0, stream>>>(S, gstart, gend, psum, pmax);
    k_final<<<BB, 64, 0, stream>>>(psum, pmax, gstart, gend, Wlin, blin, out);
}

// Round 11
// 649.105 us; speedup vs baseline: 1.0635x; 1.0635x over previous
//
#include <hip/hip_runtime.h>
#include <hip/hip_bf16.h>

#define NN 50000
#define EE 800000
#define DD 512
#define BB 64
#define LL 4
#define OUTC 2
#define EPSV 1e-5f

#define MTG 64                // gemm M-tile (A read exactly once over the grid)
#define BKG 64                // gemm K-step (2 mfma-K per barrier pair)
#define HV8 (NN * DD / 8)     // 3,200,000 vectorized x->fp8 items

typedef _Float16 halfx8 __attribute__((ext_vector_type(8)));
typedef float floatx4 __attribute__((ext_vector_type(4)));
typedef float floatx2 __attribute__((ext_vector_type(2)));

// ---------------- OCP e4m3 fp8 conversion (HW path on gfx950) ----------------
#if defined(__has_builtin)
#if __has_builtin(__builtin_amdgcn_cvt_pk_f32_fp8) && __has_builtin(__builtin_amdgcn_cvt_pk_fp8_f32)
#define HW_FP8 1
#endif
#endif

#ifdef HW_FP8
__device__ __forceinline__ floatx2 f8x2_lo(unsigned int u) {
    return __builtin_amdgcn_cvt_pk_f32_fp8(u, 0);   // bytes 0,1
}
__device__ __forceinline__ floatx2 f8x2_hi(unsigned int u) {
    return __builtin_amdgcn_cvt_pk_f32_fp8(u, 1);   // bytes 2,3
}
__device__ __forceinline__ unsigned int f8_pack_lo(float a, float b, unsigned int old) {
    return (unsigned int)__builtin_amdgcn_cvt_pk_fp8_f32(a, b, (int)old, 0);
}
__device__ __forceinline__ unsigned int f8_pack_hi(float a, float b, unsigned int old) {
    return (unsigned int)__builtin_amdgcn_cvt_pk_fp8_f32(a, b, (int)old, 1);
}
__device__ __forceinline__ unsigned char f8_enc1(float v) {
    return (unsigned char)(__builtin_amdgcn_cvt_pk_fp8_f32(v, v, 0, 0) & 0xff);
}
#else
// software OCP e4m3fn fallback (self-consistent encode/decode)
__device__ __forceinline__ float f8_dec1(unsigned int b) {
    unsigned int s = b & 0x80u, e = (b >> 3) & 15u, m = b & 7u;
    float v = e ? __uint_as_float(((e + 120u) << 23) | (m << 20))
                : (float)m * 0.001953125f;
    return s ? -v : v;
}
__device__ __forceinline__ floatx2 f8x2_lo(unsigned int u) {
    floatx2 r; r[0] = f8_dec1(u & 0xffu); r[1] = f8_dec1((u >> 8) & 0xffu); return r;
}
__device__ __forceinline__ floatx2 f8x2_hi(unsigned int u) {
    floatx2 r; r[0] = f8_dec1((u >> 16) & 0xffu); r[1] = f8_dec1((u >> 24) & 0xffu); return r;
}
__device__ __forceinline__ unsigned char f8_enc1(float x) {
    unsigned int s = (__float_as_uint(x) >> 24) & 0x80u;
    float a = fabsf(x);
    if (a < 0.015625f) {
        int m = (int)(a * 512.0f + 0.5f);
        return (unsigned char)(s | (unsigned int)m);
    }
    unsigned int ab = __float_as_uint(a);
    int e = (int)(ab >> 23) - 127;
    unsigned int m23 = ab & 0x7fffffu;
    unsigned int r = m23 + 0x7ffffu + ((m23 >> 20) & 1u);   // RNE to 3 mantissa bits
    if (r >= 0x800000u) { e++; r -= 0x800000u; }
    unsigned int m = r >> 20;
    if (e > 8 || (e == 8 && m >= 7u)) return (unsigned char)(s | 0x7eu);  // clamp 448
    return (unsigned char)(s | ((unsigned int)(e + 7) << 3) | m);
}
__device__ __forceinline__ unsigned int f8_pack_lo(float a, float b, unsigned int old) {
    return (old & 0xffff0000u) | (unsigned int)f8_enc1(a) | ((unsigned int)f8_enc1(b) << 8);
}
__device__ __forceinline__ unsigned int f8_pack_hi(float a, float b, unsigned int old) {
    return (old & 0x0000ffffu) | ((unsigned int)f8_enc1(a) << 16) | ((unsigned int)f8_enc1(b) << 24);
}
#endif

__device__ __forceinline__ floatx4 mfma16h(halfx8 a, halfx8 b, floatx4 c) {
    return __builtin_amdgcn_mfma_f32_16x16x32_f16(a, b, c, 0, 0, 0);
}

// async global->LDS, 16B per lane. LDS dest = wave-uniform base + lane*16.
__device__ __forceinline__ void ldg2lds16(const _Float16* g, _Float16* l) {
    __builtin_amdgcn_global_load_lds(
        (const __attribute__((address_space(1))) unsigned int*)g,
        (__attribute__((address_space(3))) unsigned int*)l, 16, 0, 0);
}

// SWIZZLE SCHEME (G21: gload_lds writes linearly -> pre-swizzle in GLOBAL,
// unswizzle on ds_read). All GEMM-consumed fp16 rows (S and WT) are stored
// with their 16-B granules XOR-permuted by (row&7) WITHIN each 128-B window.
// Producers stay fully coalesced (pure lane permutation); the ds_read_b128
// then lands exactly 8 words/bank = the wave64 b128 floor.

// ---------------- fused prep: x->fp8 + WT transpose (pre-swizzled) + BN fold +
// packed u64 edge atomics (fire-and-forget: no returned value -> no chain) ----
__global__ void k_prep(const float* __restrict__ x, const float* __restrict__ Wc,
                       const int* __restrict__ ei, const int* __restrict__ sd,
                       const float* __restrict__ bc, const float* __restrict__ gamma,
                       const float* __restrict__ beta, const float* __restrict__ rmean,
                       const float* __restrict__ rvar,
                       unsigned char* __restrict__ X8, _Float16* __restrict__ WT,
                       unsigned long long* __restrict__ degcnt,
                       float* __restrict__ scb, float* __restrict__ shb) {
    int i = blockIdx.x * blockDim.x + threadIdx.x;
    if (i < HV8) {
        const float4* xp = (const float4*)x + (size_t)i * 2;
        float4 v0 = xp[0], v1 = xp[1];
        unsigned int u0 = 0, u1 = 0;
        u0 = f8_pack_lo(v0.x, v0.y, u0);
        u0 = f8_pack_hi(v0.z, v0.w, u0);
        u1 = f8_pack_lo(v1.x, v1.y, u1);
        u1 = f8_pack_hi(v1.z, v1.w, u1);
        uint2 q; q.x = u0; q.y = u1;
        ((uint2*)X8)[i] = q;
    }
    if (i < LL * DD * DD) {
        // i = (l<<18)+(n<<9)+k, k fastest -> coalesced write (pure lane perm);
        // granule swizzle: k bits 3..5 ^= n&7 (stays inside the 64-half window)
        int l = i >> 18;
        int rem = i & ((DD * DD) - 1);
        int n = rem >> 9;
        int k = rem & (DD - 1);
        WT[(l << 18) + (n << 9) + (k ^ ((n & 7) << 3))] =
            (_Float16)Wc[(l << 18) + (k << 9) + n];
    }
    if (i < LL * DD) {
        // out = gamma*(agg + bc - rmean)*rs + beta = sc*agg + sh
        float rs = rsqrtf(rvar[i] + EPSV);
        float scv = gamma[i] * rs;
        scb[i] = scv;
        shb[i] = scv * (bc[i] - rmean[i]) + beta[i];
    }
    if ((i & 3) == 0) {
        int e = i >> 2;
        if (e < EE) {
            int c = ei[EE + e];
            unsigned long long v =
                0x100000000ull + (unsigned long long)((sd[e] == 1) ? 10u : 7u);
            atomicAdd(&degcnt[c], v);
        }
    }
}

// ---------------- scan block 1 (+ fused dis + fused graph bounds) ----------------
__global__ void k_scan1(const unsigned long long* __restrict__ degcnt,
                        int* __restrict__ rowptr, int* __restrict__ bsum,
                        float* __restrict__ dis, const int* __restrict__ batch,
                        int* __restrict__ gstart, int* __restrict__ gend) {
    __shared__ int sh[256];
    const int t = threadIdx.x;
    const int i = blockIdx.x * 256 + t;
    int cntv = 0;
    if (i < NN) {
        unsigned long long dc = degcnt[i];
        cntv = (int)(dc >> 32);
        float degv = 0.1f * (float)(unsigned int)(dc & 0xffffffffu);
        dis[i] = rsqrtf(fmaxf(degv + 1.0f, EPSV));   // +1 = self-loop weight
        int g = batch[i];
        int gp = (i == 0) ? -1 : batch[i - 1];
        if (g != gp) gstart[g] = i;
        int gn = (i == NN - 1) ? BB : batch[i + 1];
        if (g != gn) gend[g] = i + 1;
    }
    sh[t] = cntv;
    __syncthreads();
    for (int off = 1; off < 256; off <<= 1) {
        int y = (t >= off) ? sh[t - off] : 0;
        __syncthreads();
        if (t >= off) sh[t] += y;
        __syncthreads();
    }
    if (i < NN) rowptr[i] = sh[t] - cntv;   // exclusive
    if (t == 255) bsum[blockIdx.x] = sh[255];
}

// parallel single-block scan over the 196 block sums
__global__ void k_scan2(int* __restrict__ bsum, int* __restrict__ rowptr, int nb) {
    __shared__ int sh[256];
    const int t = threadIdx.x;
    int v = (t < nb) ? bsum[t] : 0;
    sh[t] = v;
    __syncthreads();
    for (int off = 1; off < 256; off <<= 1) {
        int y = (t >= off) ? sh[t - off] : 0;
        __syncthreads();
        if (t >= off) sh[t] += y;
        __syncthreads();
    }
    if (t < nb) bsum[t] = sh[t] - v;    // exclusive
    if (t == 255) rowptr[NN] = sh[255]; // total
}

__global__ void k_scan3(int* __restrict__ rowptr, const int* __restrict__ bsum) {
    int i = blockIdx.x * blockDim.x + threadIdx.x;
    if (i < NN) rowptr[i] += bsum[i >> 8];
}

// ---------------- CSR fill: packed (src, norm) uint2, one edge/thread --------
// R9-exact (measured < 62 us). R10's 4-edge ILP variant REGRESSED to 72 us:
// grid/4 -> occupancy 52% -> 18%, too few waves to cover atomic latency
// (TLP loss > ILP gain). Full 3125-block grid is the proven regime.
__global__ void k_fill(const int* __restrict__ ei, const int* __restrict__ sd,
                       const float* __restrict__ dis, const int* __restrict__ rowptr,
                       int* __restrict__ fill, uint2* __restrict__ edges) {
    int e = blockIdx.x * blockDim.x + threadIdx.x;
    if (e >= EE) return;
    int s = ei[e];
    int c = ei[EE + e];
    float w = (sd[e] == 1) ? 1.0f : 0.7f;
    int p = rowptr[c] + atomicAdd(&fill[c], 1);
    uint2 ev;
    ev.x = (unsigned int)s;
    ev.y = __float_as_uint(dis[s] * w * dis[c]);
    edges[p] = ev;
}

// ---------------- split gather: S[n] = sum norm_e * H8[src] + dn^2 * H8[n] ----
// Measured pattern floor: ~62 us @ ~3.95 TB/s, FETCH ~190 MB (R5/R7/R9; two
// cache-model attacks failed -- R7 channel-split and R2-era fusion).
__launch_bounds__(256)
__global__ void k_agg(const unsigned char* __restrict__ h8, const int* __restrict__ rowptr,
                      const uint2* __restrict__ edges,
                      const float* __restrict__ dis, _Float16* __restrict__ S) {
    const int n = blockIdx.x * 4 + (threadIdx.x >> 6);
    const int lane = threadIdx.x & 63;
    if (n >= NN) return;
    const float dn = dis[n];
    const float sw = dn * dn;  // self-loop norm
    uint2 q = ((const uint2*)(h8 + (size_t)n * DD))[lane];
    floatx2 acc[4];
    acc[0] = f8x2_lo(q.x) * sw;
    acc[1] = f8x2_hi(q.x) * sw;
    acc[2] = f8x2_lo(q.y) * sw;
    acc[3] = f8x2_hi(q.y) * sw;
    const int s0 = rowptr[n], s1 = rowptr[n + 1];
    int i = s0;
    for (; i + 8 <= s1; i += 8) {
        uint2 ev[8];
        uint2 qv[8];
#pragma unroll
        for (int u = 0; u < 8; u++) ev[u] = edges[i + u];
#pragma unroll
        for (int u = 0; u < 8; u++)
            qv[u] = ((const uint2*)(h8 + (size_t)ev[u].x * DD))[lane];
#pragma unroll
        for (int u = 0; u < 8; u++) {
            const float wv = __uint_as_float(ev[u].y);
            acc[0] += f8x2_lo(qv[u].x) * wv;
            acc[1] += f8x2_hi(qv[u].x) * wv;
            acc[2] += f8x2_lo(qv[u].y) * wv;
            acc[3] += f8x2_hi(qv[u].y) * wv;
        }
    }
    for (; i + 4 <= s1; i += 4) {
        uint2 ev[4];
        uint2 qv[4];
#pragma unroll
        for (int u = 0; u < 4; u++) ev[u] = edges[i + u];
#pragma unroll
        for (int u = 0; u < 4; u++)
            qv[u] = ((const uint2*)(h8 + (size_t)ev[u].x * DD))[lane];
#pragma unroll
        for (int u = 0; u < 4; u++) {
            const float wv = __uint_as_float(ev[u].y);
            acc[0] += f8x2_lo(qv[u].x) * wv;
            acc[1] += f8x2_hi(qv[u].x) * wv;
            acc[2] += f8x2_lo(qv[u].y) * wv;
            acc[3] += f8x2_hi(qv[u].y) * wv;
        }
    }
    for (; i < s1; i++) {
        uint2 ev = edges[i];
        uint2 qb = ((const uint2*)(h8 + (size_t)ev.x * DD))[lane];
        const float wn = __uint_as_float(ev.y);
        acc[0] += f8x2_lo(qb.x) * wn;
        acc[1] += f8x2_hi(qb.x) * wn;
        acc[2] += f8x2_lo(qb.y) * wn;
        acc[3] += f8x2_hi(qb.y) * wn;
    }
    halfx8 hv;
#pragma unroll
    for (int k = 0; k < 4; k++) {
        hv[2 * k] = (_Float16)acc[k][0];
        hv[2 * k + 1] = (_Float16)acc[k][1];
    }
    // granule-swizzled coalesced row store (lane permutation within 128-B wins)
    ((halfx8*)(S + (size_t)n * DD))[lane ^ (n & 7)] = hv;
}

// ---------------- GEMM (R5 K-loop + packed epilogue + fused pooling) ---------
// K-loop is R5-exact: MTG=64 x full-N 512, BKG=64, granule-XOR ds_reads at the
// 8-words/bank floor. LDS-bounce epilogue (R7, -42 us): stage C into dead sB,
// store full contiguous rows. NEW (OUT8=0): mean/max pooling fused into the
// epilogue -- the block's 64-row fp16 C tile is already in LDS, so thread t
// (== column t) walks the 64 rows (batch sorted -> ~1.08 graphs/block) and
// flushes ~2 atomic pairs; kills k_pool's 51.2 MB re-read + one launch.
// Pooling inputs are the identical post-fp16-cast values k_pool read.
// OUT8=0 writes fp16 in-place over A rows (block-row-exclusive).
template <int OUT8>
__launch_bounds__(512)
__global__ void k_gemm(const _Float16* __restrict__ A,
                       const _Float16* __restrict__ B,   // WT layer base, [n][k] swz
                       const float* __restrict__ sc, const float* __restrict__ sh,
                       _Float16* __restrict__ C16, unsigned char* __restrict__ C8,
                       const int* __restrict__ batch,
                       float* __restrict__ psum, unsigned int* __restrict__ pmax) {
    __shared__ _Float16 sA[MTG * BKG];   // 8 KB (reused as graph-id cache)
    __shared__ _Float16 sB[512 * BKG];   // 64 KB (reused as C bounce)

    const int t = threadIdx.x;
    const int wid = t >> 6;          // 0..7
    const int lane = t & 63;
    const int l15 = lane & 15;
    const int quad = lane >> 4;
    const int m0 = blockIdx.x * MTG;
    const int wc = wid * 64;         // wave col base (8 x 64 = 512)
    const int key = l15 & 7;         // row&7 for every fragment row this lane reads

    // A staging: 512 thr x 16 B = 64 rows x 128 B; row t>>3, granule t&7
    int arow = m0 + (t >> 3);
    if (arow > NN - 1) arow = NN - 1;   // clamp loads; stores guarded
    const _Float16* gA = A + (size_t)arow * DD + (t & 7) * 8;
    _Float16* lA = sA + t * 8;
    // B staging: 8 rounds of 64 rows x 128 B
    const _Float16* gB = B + (size_t)(t >> 3) * DD + (t & 7) * 8;
    _Float16* lB = sB + t * 8;

    floatx4 acc[4][4];
#pragma unroll
    for (int i = 0; i < 4; i++)
#pragma unroll
        for (int j = 0; j < 4; j++) acc[i][j] = (floatx4){0.f, 0.f, 0.f, 0.f};

    for (int k0 = 0; k0 < DD; k0 += BKG) {
        __syncthreads();   // previous compute done before overwriting LDS
        ldg2lds16(gA + k0, lA);
#pragma unroll
        for (int r = 0; r < 8; r++)
            ldg2lds16(gB + (size_t)r * 64 * DD + k0, lB + r * 4096);
        __syncthreads();   // compiler drains vmcnt before barrier

#pragma unroll
        for (int cc = 0; cc < 2; cc++) {
            halfx8 a[4], b[4];
            const int goff = ((cc * 4 + quad) ^ key) * 8;   // unswizzle granule
#pragma unroll
            for (int i = 0; i < 4; i++)
                a[i] = *(const halfx8*)&sA[(i * 16 + l15) * BKG + goff];
#pragma unroll
            for (int j = 0; j < 4; j++)
                b[j] = *(const halfx8*)&sB[(wc + j * 16 + l15) * BKG + goff];
#pragma unroll
            for (int i = 0; i < 4; i++)
#pragma unroll
                for (int j = 0; j < 4; j++)
                    acc[i][j] = mfma16h(a[i], b[j], acc[i][j]);
        }
    }

    // ---- packed epilogue: affine+ReLU -> bounce (sB) -> wide row stores ----
    __syncthreads();                 // all sA/sB fragment reads complete
    _Float16* bounce = sB;           // [64 rows][512 halves], granule-XOR row&7
    int* sgid = (int*)sA;            // sA dead after K-loop: 64 graph ids
    if (!OUT8 && t < 64) {
        const int grow = m0 + t;
        sgid[t] = (grow < NN) ? batch[grow] : -1;
    }
#pragma unroll
    for (int j = 0; j < 4; j++) {
        const int gcol = wc + j * 16 + l15;
        const float scv = sc[gcol];
        const float shv = sh[gcol];
#pragma unroll
        for (int i = 0; i < 4; i++) {
#pragma unroll
            for (int r = 0; r < 4; r++) {
                const int row = i * 16 + quad * 4 + r;
                float v = fmaxf(fmaf(scv, acc[i][j][r], shv), 0.f);
                bounce[row * DD + (gcol ^ ((row & 7) << 3))] = (_Float16)v;
            }
        }
    }
    __syncthreads();
    if (OUT8) {
        // fp8 out: 4 iters; half-wave writes a full contiguous 512 B row
#pragma unroll
        for (int p = 0; p < 4; p++) {
            const int G = p * 512 + t;
            const int row = G >> 5;
            const int c = G & 31;              // 16-byte output granule in row
            const int rk = row & 7;
            const int g0 = (2 * c) ^ rk;       // halves 16c..16c+7 live here
            halfx8 ha = *(const halfx8*)&bounce[row * DD + g0 * 8];
            halfx8 hb = *(const halfx8*)&bounce[row * DD + (g0 ^ 1) * 8];
            unsigned int u0 = 0, u1 = 0, u2 = 0, u3 = 0;
            u0 = f8_pack_lo((float)ha[0], (float)ha[1], u0);
            u0 = f8_pack_hi((float)ha[2], (float)ha[3], u0);
            u1 = f8_pack_lo((float)ha[4], (float)ha[5], u1);
            u1 = f8_pack_hi((float)ha[6], (float)ha[7], u1);
            u2 = f8_pack_lo((float)hb[0], (float)hb[1], u2);
            u2 = f8_pack_hi((float)hb[2], (float)hb[3], u2);
            u3 = f8_pack_lo((float)hb[4], (float)hb[5], u3);
            u3 = f8_pack_hi((float)hb[6], (float)hb[7], u3);
            const int grow = m0 + row;
            if (grow < NN) {
                uint4 qo; qo.x = u0; qo.y = u1; qo.z = u2; qo.w = u3;
                *(uint4*)(C8 + (size_t)grow * DD + c * 16) = qo;
            }
        }
    } else {
        // fp16 out: 8 iters; wave writes a full contiguous 1024 B row
#pragma unroll
        for (int p = 0; p < 8; p++) {
            const int g = p * 512 + t;
            const int row = g >> 6;
            const int c8 = g & 63;             // 8-half output granule in row
            const int grow = m0 + row;
            if (grow < NN) {
                halfx8 hv = *(const halfx8*)
                    &bounce[row * DD + ((c8 ^ (row & 7)) << 3)];
                *(halfx8*)(C16 + (size_t)grow * DD + c8 * 8) = hv;
            }
        }
        // ---- fused pooling: thread t == column t, walk the block's rows ----
        const int c = t;
        float sum = 0.f, mx = 0.f;
        int curg = sgid[0];
        for (int r = 0; r < MTG; r++) {
            if (m0 + r >= NN) break;
            const int gid = sgid[r];
            if (gid != curg) {
                atomicAdd(&psum[curg * DD + c], sum);
                atomicMax(&pmax[curg * DD + c], __float_as_uint(fmaxf(mx, 0.f)));
                sum = 0.f; mx = 0.f; curg = gid;
            }
            float v = (float)bounce[r * DD + (c ^ ((r & 7) << 3))];
            sum += v;
            mx = fmaxf(mx, v);
        }
        atomicAdd(&psum[curg * DD + c], sum);
        atomicMax(&pmax[curg * DD + c], __float_as_uint(fmaxf(mx, 0.f)));
    }
}

// ---------------- final linear + log_softmax: one wave per graph ----------------
__launch_bounds__(64)
__global__ void k_final(const float* __restrict__ psum, const unsigned int* __restrict__ pmax,
                        const int* __restrict__ gstart, const int* __restrict__ gend,
                        const float* __restrict__ Wlin, const float* __restrict__ blin,
                        float* __restrict__ out) {
    const int g = blockIdx.x;
    const int lane = threadIdx.x;
    int cntg = gend[g] - gstart[g];
    if (cntg < 1) cntg = 1;   // empty graph: psum/pmax are 0, inv irrelevant
    const float inv = 1.0f / (float)cntg;
    float z0 = 0.f, z1 = 0.f;
#pragma unroll
    for (int j = 0; j < 8; j++) {
        const int k = j * 64 + lane;
        float mean = psum[g * DD + k] * inv;
        float mx = __uint_as_float(pmax[g * DD + k]);
        z0 += mean * Wlin[k * OUTC + 0] + mx * Wlin[(DD + k) * OUTC + 0];
        z1 += mean * Wlin[k * OUTC + 1] + mx * Wlin[(DD + k) * OUTC + 1];
    }
#pragma unroll
    for (int off = 32; off > 0; off >>= 1) {
        z0 += __shfl_down(z0, off);
        z1 += __shfl_down(z1, off);
    }
    if (lane == 0) {
        z0 += blin[0];
        z1 += blin[1];
        float m = fmaxf(z0, z1);
        float ls = m + logf(expf(z0 - m) + expf(z1 - m));
        out[g * OUTC + 0] = z0 - ls;
        out[g * OUTC + 1] = z1 - ls;
    }
}

extern "C" void kernel_launch(void* const* d_in, const int* in_sizes, int n_in,
                              void* d_out, int out_size, void* d_ws, size_t ws_size,
                              hipStream_t stream) {
    const float* x = (const float*)d_in[0];
    const int* ei = (const int*)d_in[1];
    const int* batch = (const int*)d_in[2];
    const int* sd = (const int*)d_in[3];
    const float* Wc = (const float*)d_in[4];
    const float* bc = (const float*)d_in[5];
    const float* gamma = (const float*)d_in[6];
    const float* beta = (const float*)d_in[7];
    const float* rmean = (const float*)d_in[8];
    const float* rvar = (const float*)d_in[9];
    const float* Wlin = (const float*)d_in[10];
    const float* blin = (const float*)d_in[11];
    float* out = (float*)d_out;

    char* p = (char*)d_ws;
    auto alloc = [&](size_t bytes) {
        char* r = p;
        p += (bytes + 255) & ~(size_t)255;
        return r;
    };
    // All buffers DISJOINT (gather reads X8 while writing S concurrently).
    _Float16* S = (_Float16*)alloc((size_t)NN * DD * 2);        // 51.2 MB
    unsigned char* X8a = (unsigned char*)alloc((size_t)NN * DD);// 25.6 MB
    unsigned char* X8b = (unsigned char*)alloc((size_t)NN * DD);// 25.6 MB
    _Float16* WT = (_Float16*)alloc((size_t)LL * DD * DD * 2);
    float* scb = (float*)alloc(LL * DD * 4);
    float* shb = (float*)alloc(LL * DD * 4);
    uint2* edges = (uint2*)alloc((size_t)EE * 8);   // fully written by k_fill (no zeroing)
    // --- zero-initialized region starts here (hipMemsetAsync) ---
    char* zbase = p;
    unsigned long long* degcnt = (unsigned long long*)alloc(NN * 8);
    float* dis = (float*)alloc(NN * 4);
    int* fill = (int*)alloc(NN * 4);
    int* rowptr = (int*)alloc((NN + 1) * 4);
    int* bsum = (int*)alloc(256 * 4);
    int* gstart = (int*)alloc(BB * 4);
    int* gend = (int*)alloc(BB * 4);
    float* psum = (float*)alloc(BB * DD * 4);
    unsigned int* pmax = (unsigned int*)alloc(BB * DD * 4);
    size_t zbytes = (size_t)(p - zbase);
    (void)ws_size; (void)in_sizes; (void)n_in; (void)out_size;

    const int nb256 = (NN + 255) / 256;          // 196
    const int eb256 = (EE + 255) / 256;          // 3125

    hipMemsetAsync(zbase, 0, zbytes, stream);
    k_prep<<<(HV8 + 255) / 256, 256, 0, stream>>>(x, Wc, ei, sd, bc, gamma, beta,
                                                  rmean, rvar, X8a, WT, degcnt, scb, shb);
    k_scan1<<<nb256, 256, 0, stream>>>(degcnt, rowptr, bsum, dis, batch, gstart, gend);
    k_scan2<<<1, 256, 0, stream>>>(bsum, rowptr, nb256);
    k_scan3<<<nb256, 256, 0, stream>>>(rowptr, bsum);
    k_fill<<<eb256, 256, 0, stream>>>(ei, sd, dis, rowptr, fill, edges);

    const int ggrid = (NN + MTG - 1) / MTG;   // 782 blocks
    unsigned char* bufs[2] = {X8a, X8b};
    int cur = 0;
    for (int l = 0; l < LL; l++) {
        k_agg<<<(NN + 3) / 4, 256, 0, stream>>>(bufs[cur], rowptr, edges, dis, S);
        if (l < LL - 1)
            k_gemm<1><<<ggrid, 512, 0, stream>>>(S, WT + (size_t)l * DD * DD,
                                                 scb + l * DD, shb + l * DD,
                                                 nullptr, bufs[cur ^ 1],
                                                 nullptr, nullptr, nullptr);
        else
            k_gemm<0><<<ggrid, 512, 0, stream>>>(S, WT + (size_t)l * DD * DD,
                                                 scb + l * DD, shb + l * DD,
                                                 S, nullptr,
                                                 batch, psum, pmax);
        cur ^= 1;
    }

    k_final<<<BB, 64, 0, stream>>>(psum, pmax, gstart, gend, Wlin, blin, out);
}